// Round 7
// baseline (540.742 us; speedup 1.0000x reference)
//
#include <hip/hip_runtime.h>
#include <math.h>

// Problem constants
#define BS 4
#define LQ 1024
#define EMB 256
#define NH 8
#define NL 4
#define NP 16
#define HD 32
#define LV 5440     // 64*64 + 32*32 + 16*16 + 8*8
#define LVP 5936    // padded: 66^2 + 34^2 + 18^2 + 10^2
#define KDIM 256    // all GEMMs have K = 256

#define TAIL_GRID 720   // %8==0 (head/XCD affinity), <= 768 residency cap @3/CU

typedef __attribute__((ext_vector_type(8))) short short8;  // 8 bf16 = 4 VGPRs
typedef __attribute__((ext_vector_type(4))) float f32x4;

__device__ inline unsigned short f2bf(float f) {
    unsigned u = __builtin_bit_cast(unsigned, f);
    u += 0x7fff + ((u >> 16) & 1);   // round-to-nearest-even
    return (unsigned short)(u >> 16);
}

// Fragment-major layout for a row-major [R][256] bf16 matrix:
//   tile t = (r>>4)*8 + (k>>5); slot = (r&15)+16*((k>>3)&3); elem = k&7
//   offset = t*512 + slot*8 + elem   -> one 1KB wave burst per MFMA fragment.
// v_pad layout (HEAD-MAJOR): [h][b][lvl-plane][y][x][32ch].
// R2 LESSON: LDS-staging lvl2+3 regressed — gathers already cache-hits.
// R3 LESSON: coord-hoist neutral — sample not VALU-bound.
// R4 LESSON: 8 waves/SIMD neutral — sample at structural floor since R0.
// R5 WIN: outp 64->256 blocks + fused 12 waves/CU = -4.3us.
// R6 LESSON: hipLaunchCooperativeKernel silently no-ops under the harness's
//   graph capture (output stayed zero => absmax == max|ref|). Launch fusion
//   redone here with REGULAR launches + software grid barrier:
//   all 720 blocks resident (3/CU @ VGPR<=168, m97 precedent), AGENT-scope
//   atomics for the counter (volatile poll would spin on stale per-XCD L2).

// ---------------- software grid barrier (all blocks resident) --------------------
__device__ __forceinline__ void gridbar(unsigned* cnt, unsigned n) {
    __threadfence();                 // agent-scope release of this thread's writes
    __syncthreads();
    if (threadIdx.x == 0) {
        __hip_atomic_fetch_add(cnt, 1u, __ATOMIC_ACQ_REL, __HIP_MEMORY_SCOPE_AGENT);
        while (__hip_atomic_load(cnt, __ATOMIC_RELAXED, __HIP_MEMORY_SCOPE_AGENT) < n)
            __builtin_amdgcn_s_sleep(16);
    }
    __syncthreads();
    __threadfence();                 // agent-scope acquire side
}

// ---------------- prep ------------------------------------------------------------
__global__ __launch_bounds__(256) void prep(const float* __restrict__ Wv,
                                            const float* __restrict__ Wo,
                                            const float* __restrict__ Wa,
                                            const float* __restrict__ Wu,
                                            const float* __restrict__ value,
                                            const float* __restrict__ query,
                                            unsigned short* __restrict__ Wt,
                                            unsigned short* __restrict__ val_bf,
                                            unsigned short* __restrict__ qry_bf,
                                            unsigned short* __restrict__ v_pad,
                                            unsigned* __restrict__ bar) {
    const int blk = blockIdx.x;
    const int t = threadIdx.x;
    if (blk == 0 && t == 0) { bar[0] = 0u; bar[1] = 0u; }   // re-zero every iter
    if (blk < 512) {
        __shared__ float tile[32][33];     // [k_local][n_local]
        const int n0 = (blk & 63) * 32, k0 = (blk >> 6) * 32;
        const float* src; int N, nloc;
        if (n0 < 256)       { src = Wv; N = 256;  nloc = n0; }
        else if (n0 < 1280) { src = Wo; N = 1024; nloc = n0 - 256; }
        else if (n0 < 1792) { src = Wa; N = 512;  nloc = n0 - 1280; }
        else                { src = Wu; N = 256;  nloc = n0 - 1792; }
        const int tx = t & 31, ty = t >> 5;  // ty 0..7
#pragma unroll
        for (int i = 0; i < 32; i += 8)
            tile[ty + i][tx] = src[(size_t)(k0 + ty + i) * N + nloc + tx];
        __syncthreads();
        if (t < 128) {                       // 32 n x 4 k-octets
            const int n_loc = t & 31, oct = t >> 5;
            const int n = n0 + n_loc;
            short8 h;
#pragma unroll
            for (int e = 0; e < 8; ++e) h[e] = (short)f2bf(tile[oct * 8 + e][n_loc]);
            const size_t off = ((size_t)(n >> 4) * 8 + (k0 >> 5)) * 512
                             + ((n & 15) + 16 * oct) * 8;
            *(short8*)(Wt + off) = h;
        }
    } else if (blk < 3744) {
        // fragment-major fp32->bf16: thread = (row, k-octet)
        int i; const float* src; unsigned short* dst;
        if (blk < 3232) { i = (blk - 512) * 256 + t;  src = value; dst = val_bf; }
        else            { i = (blk - 3232) * 256 + t; src = query; dst = qry_bf; }
        const int r = i >> 5, oct = i & 31, k0 = oct * 8;
        const float4 f0 = *(const float4*)(src + (size_t)r * KDIM + k0);
        const float4 f1 = *(const float4*)(src + (size_t)r * KDIM + k0 + 4);
        short8 h;
        h[0] = (short)f2bf(f0.x); h[1] = (short)f2bf(f0.y);
        h[2] = (short)f2bf(f0.z); h[3] = (short)f2bf(f0.w);
        h[4] = (short)f2bf(f1.x); h[5] = (short)f2bf(f1.y);
        h[6] = (short)f2bf(f1.z); h[7] = (short)f2bf(f1.w);
        const size_t off = ((size_t)(r >> 4) * 8 + (oct >> 2)) * 512
                         + ((r & 15) + 16 * (oct & 3)) * 8;
        *(short8*)(dst + off) = h;
    } else {
        // zero border pixels of padded v (4 batches x 496 border pixels).
        // head-major: lane32 = head*4 + channel-quad, 16B per lane.
        const int pidx = (blk - 3744) * 8 + (t >> 5);   // 0..1983
        const int lane32 = t & 31;
        const unsigned b = (unsigned)pidx / 496u;
        const unsigned rem = (unsigned)pidx - b * 496u;
        int Wd, W2, pb, i;
        if (rem < 260)      { Wd = 64; W2 = 66; pb = 0;    i = rem; }
        else if (rem < 392) { Wd = 32; W2 = 34; pb = 4356; i = rem - 260; }
        else if (rem < 460) { Wd = 16; W2 = 18; pb = 5512; i = rem - 392; }
        else                { Wd = 8;  W2 = 10; pb = 5836; i = rem - 460; }
        int y, x;
        if (i < W2)          { y = 0;      x = i; }
        else if (i < 2 * W2) { y = Wd + 1; x = i - W2; }
        else { const int j = i - 2 * W2; y = 1 + (j >> 1); x = (j & 1) ? (Wd + 1) : 0; }
        const int hh = lane32 >> 2, cq = lane32 & 3;
        const size_t off = (((size_t)(hh * BS + b) * LVP + pb + y * W2 + x) << 5)
                         + cq * 8;
        uint4 z = {0, 0, 0, 0};
        *(uint4*)(v_pad + off) = z;
    }
}

// ---------------- barrier-free no-LDS bf16 MFMA GEMM, 128x128 tile ---------------
template <int MODE>
__device__ __forceinline__ void gemm_nolds(const unsigned short* __restrict__ A,
                                           const unsigned short* __restrict__ Bt,
                                           const float* __restrict__ bias,
                                           const float* __restrict__ bias2,
                                           const float* __restrict__ refp,
                                           void* __restrict__ Cv,
                                           float* __restrict__ C2,
                                           int N, int bx, int by) {
    const int t = threadIdx.x;
    const int lane = t & 63, w = t >> 6;
    const int quad = lane >> 4, l16 = lane & 15;
    const int wr = w >> 1, wc = w & 1;
    const int row0 = by * 128, col0 = bx * 128;

    const unsigned short* ap = A  + ((size_t)((row0 >> 4) + wr * 4) * 8) * 512 + lane * 8;
    const unsigned short* bp = Bt + ((size_t)((col0 >> 4) + wc * 4) * 8) * 512 + lane * 8;

    f32x4 acc[4][4] = {};

#pragma unroll 2
    for (int kt = 0; kt < 8; ++kt) {
        short8 af[4], bf[4];
#pragma unroll
        for (int mi = 0; mi < 4; ++mi)
            af[mi] = *(const short8*)(ap + (size_t)mi * 4096 + kt * 512);
#pragma unroll
        for (int ni = 0; ni < 4; ++ni)
            bf[ni] = *(const short8*)(bp + (size_t)ni * 4096 + kt * 512);
#pragma unroll
        for (int mi = 0; mi < 4; ++mi)
#pragma unroll
            for (int ni = 0; ni < 4; ++ni)
                acc[mi][ni] = __builtin_amdgcn_mfma_f32_16x16x32_bf16(af[mi], bf[ni],
                                                                      acc[mi][ni], 0, 0, 0);
    }

    // C/D layout: col = lane&15, row = quad*4 + reg  [m89-verified, R2-R6 verified]
    if (MODE == 0) {
#pragma unroll
        for (int ni = 0; ni < 4; ++ni) {
            const int c = col0 + wc * 64 + ni * 16 + l16;
            const float bv = bias[c];
#pragma unroll
            for (int mi = 0; mi < 4; ++mi) {
                const int r0 = row0 + wr * 64 + mi * 16 + quad * 4;
#pragma unroll
                for (int rr = 0; rr < 4; ++rr)
                    ((float*)Cv)[(size_t)(r0 + rr) * N + c] = acc[mi][ni][rr] + bv;
            }
        }
    } else if (MODE == 2) {
        // v-projection into padded HEAD-MAJOR layout:
        // elem = ((head*BS + b)*LVP + pb + (y+1)*W2 + (x+1))*32 + (c&31)
        unsigned short* C = (unsigned short*)Cv;
        float bv[4];
        int cc[4];
#pragma unroll
        for (int ni = 0; ni < 4; ++ni) {
            cc[ni] = col0 + wc * 64 + ni * 16 + l16;
            bv[ni] = bias[cc[ni]];
        }
#pragma unroll
        for (int mi = 0; mi < 4; ++mi) {
#pragma unroll
            for (int rr = 0; rr < 4; ++rr) {
                const unsigned r = row0 + wr * 64 + mi * 16 + quad * 4 + rr;
                const unsigned b = r / 5440u;
                const unsigned flat = r - b * 5440u;
                unsigned y, x, W2, pb;
                if (flat < 4096)      { y = flat >> 6; x = flat & 63; W2 = 66; pb = 0; }
                else if (flat < 5120) { const unsigned f = flat - 4096; y = f >> 5; x = f & 31; W2 = 34; pb = 4356; }
                else if (flat < 5376) { const unsigned f = flat - 5120; y = f >> 4; x = f & 15; W2 = 18; pb = 5512; }
                else                  { const unsigned f = flat - 5376; y = f >> 3; x = f & 7;  W2 = 10; pb = 5836; }
                const size_t pix = (size_t)(pb + (y + 1) * W2 + (x + 1)) << 5;
#pragma unroll
                for (int ni = 0; ni < 4; ++ni) {
                    const int cc_ = cc[ni];
                    const size_t off = (((size_t)((cc_ >> 5) * BS + b) * LVP) << 5)
                                     + pix + (cc_ & 31);
                    C[off] = f2bf(acc[mi][ni][rr] + bv[ni]);
                }
            }
        }
    } else {
        const bool is_off = (col0 < 1024);   // block-uniform (1024 % 128 == 0)
        if (is_off) {
            float* C = (float*)Cv;
#pragma unroll
            for (int ni = 0; ni < 4; ++ni) {
                const int cg = col0 + wc * 64 + ni * 16 + l16;
                // cg = h*128 + l*32 + p*2 + xy
                const int xy = cg & 1, p = (cg >> 1) & 15, l = (cg >> 5) & 3;
                const float lam = (float)p * (1.0f / 15.0f);
                const float l2 = lam * lam, l3 = l2 * lam;
                const float rW = (l == 0) ? 0.015625f : (l == 1) ? 0.03125f
                                : (l == 2) ? 0.0625f : 0.125f;
                const float bv = bias[cg];
#pragma unroll
                for (int mi = 0; mi < 4; ++mi) {
                    const int r0 = row0 + wr * 64 + mi * 16 + quad * 4;
#pragma unroll
                    for (int rr = 0; rr < 4; ++rr) {
                        const int r = r0 + rr;
                        const float4 rp = *(const float4*)(refp + (size_t)r * 8 + xy * 4);
                        const float poly = rp.x * l3 + rp.y * l2 + rp.z * lam + rp.w;
                        C[(size_t)r * 1024 + cg] = poly + (acc[mi][ni][rr] + bv) * rW;
                    }
                }
            }
        } else {
            // fused softmax: this wave holds one head's 64 logits (ni*16+l16)
            // for 64 rows. Reduce over ni (in-reg) x l16 (shfl_xor 1,2,4,8).
            const int cabase = col0 - 1024 + wc * 64;   // multiple of 64
            float bv[4];
#pragma unroll
            for (int ni = 0; ni < 4; ++ni) bv[ni] = bias2[cabase + ni * 16 + l16];
#pragma unroll
            for (int mi = 0; mi < 4; ++mi) {
                const int r0 = row0 + wr * 64 + mi * 16 + quad * 4;
#pragma unroll
                for (int rr = 0; rr < 4; ++rr) {
                    float v0 = acc[mi][0][rr] + bv[0];
                    float v1 = acc[mi][1][rr] + bv[1];
                    float v2 = acc[mi][2][rr] + bv[2];
                    float v3 = acc[mi][3][rr] + bv[3];
                    float mx = fmaxf(fmaxf(v0, v1), fmaxf(v2, v3));
#pragma unroll
                    for (int mk = 1; mk < 16; mk <<= 1) mx = fmaxf(mx, __shfl_xor(mx, mk));
                    v0 = __expf(v0 - mx); v1 = __expf(v1 - mx);
                    v2 = __expf(v2 - mx); v3 = __expf(v3 - mx);
                    float s = v0 + v1 + v2 + v3;
#pragma unroll
                    for (int mk = 1; mk < 16; mk <<= 1) s += __shfl_xor(s, mk);
                    const float inv = 1.0f / s;
                    const size_t rb = (size_t)(r0 + rr) * 512 + cabase + l16;
                    C2[rb]      = v0 * inv;
                    C2[rb + 16] = v1 * inv;
                    C2[rb + 32] = v2 * inv;
                    C2[rb + 48] = v3 * inv;
                }
            }
        }
    }
}

// ---------------- sample chunk (one (h, bq0) slice of 16 groups) -----------------
__device__ __forceinline__ void sample_chunk(int sbid, int t,
                                             const unsigned short* __restrict__ v,
                                             const float* __restrict__ loc,
                                             const float* __restrict__ attn,
                                             unsigned short* __restrict__ interm) {
    const int h = sbid & 7;                     // head == XCD slot (stride%8==0)
    const int bq0 = (sbid >> 3) * 16;           // chunk's first (b,q) group

    __shared__ float4 wls[1088];                // padded: phys = idx + (idx>>4)
    __shared__ unsigned short pls[1088];        // pixel index (elem off >> 5)

    // ---- prologue: compute 1024 points' weights+offsets once ----
    {
        const int gloc = t >> 4;          // 0..15
        const int lvl  = (t >> 2) & 3;    // 0..3
        const int pq   = t & 3;           // point quad -> points pq*4..pq*4+3
        const int g = (bq0 + gloc) * 8 + h;
        const float4 l01 = *(const float4*)(loc + (size_t)g * 128 + lvl * 32 + pq * 8);
        const float4 l23 = *(const float4*)(loc + (size_t)g * 128 + lvl * 32 + pq * 8 + 4);
        const float4 av  = *(const float4*)(attn + (size_t)g * 64 + lvl * 16 + pq * 4);
        const int Wd = 64 >> lvl;
        const float Wf = (float)Wd;
        const int W2 = Wd + 2;
        const int pb = (lvl == 0) ? 0 : (lvl == 1) ? 4356 : (lvl == 2) ? 5512 : 5836;
        const int ibase = gloc * 64 + lvl * 16 + pq * 4;
        const int pbase = ibase + (ibase >> 4);      // padded physical base
        const float lx[4] = {l01.x, l01.z, l23.x, l23.z};
        const float ly[4] = {l01.y, l01.w, l23.y, l23.w};
        const float aw[4] = {av.x, av.y, av.z, av.w};
#pragma unroll
        for (int k = 0; k < 4; ++k) {
            const float x = fmaf(lx[k], Wf, -0.5f);
            const float y = fmaf(ly[k], Wf, -0.5f);
            const float xc = fminf(fmaxf(x, -1.0f), Wf);
            const float yc = fminf(fmaxf(y, -1.0f), Wf);
            const float x0f = fminf(floorf(xc), Wf - 1.0f);
            const float y0f = fminf(floorf(yc), Wf - 1.0f);
            const float wx = xc - x0f, wy = yc - y0f;
            const float iwx = 1.0f - wx, iwy = 1.0f - wy;
            const int px = (int)x0f + 1;          // [0, W]
            const int py = (int)y0f + 1;          // [0, W]
            const float a = aw[k];
            wls[pbase + k] = make_float4(iwx * iwy * a, wx * iwy * a,
                                         iwx * wy * a,  wx * wy * a);
            pls[pbase + k] = (unsigned short)(pb + py * W2 + px);
        }
    }
    __syncthreads();

    // ---- main gather loop ----
    const int bq = bq0 + (t >> 4);
    const int l16i = t & 15;
    const int lvl = l16i >> 2;                  // level 0..3
    const int cq  = l16i & 3;                   // channel octet (8 bf16)
    const int b = bq >> 10;                     // chunk-uniform (16 | 1024)
    const int rowoff = ((64 >> lvl) + 2) * 32;  // next-row elem stride

    const unsigned short* vl = v + (((size_t)(h * BS + b) * LVP) << 5) + cq * 8;
    const int wbase = (t >> 4) * 64 + lvl * 16;
    const int wphys = wbase + (wbase >> 4);     // (idx>>4) const over p in [0,16)

    float2 acc2[4] = {};

    auto cvt2 = [](unsigned d) {
        uint2 u; u.x = d << 16; u.y = d & 0xffff0000u;
        return __builtin_bit_cast(float2, u);
    };
    auto cadd = [&](const uint4 q, float wgt) {
        const float2 w2 = make_float2(wgt, wgt);
        acc2[0] += cvt2(q.x) * w2;
        acc2[1] += cvt2(q.y) * w2;
        acc2[2] += cvt2(q.z) * w2;
        acc2[3] += cvt2(q.w) * w2;
    };

#pragma unroll 1
    for (int p = 0; p < 16; ++p) {
        const float4 w = wls[wphys + p];
        const int base = ((int)pls[wphys + p]) << 5;
        const unsigned short* ptr = vl + base;
        const uint4 g00 = *(const uint4*)(ptr);
        const uint4 g10 = *(const uint4*)(ptr + 32);
        const uint4 g01 = *(const uint4*)(ptr + rowoff);
        const uint4 g11 = *(const uint4*)(ptr + rowoff + 32);
        cadd(g00, w.x); cadd(g10, w.y); cadd(g01, w.z); cadd(g11, w.w);
    }

    float a[8] = {acc2[0].x, acc2[0].y, acc2[1].x, acc2[1].y,
                  acc2[2].x, acc2[2].y, acc2[3].x, acc2[3].y};
    // reduce across the 4 level-quads (lane bits 2,3)
#pragma unroll
    for (int m = 4; m <= 8; m <<= 1)
#pragma unroll
        for (int k = 0; k < 8; ++k) a[k] += __shfl_xor(a[k], m);

    if (lvl == 0) {
        unsigned short o[8];
#pragma unroll
        for (int k = 0; k < 8; ++k) o[k] = f2bf(a[k]);
        // fragment-major interm: row = bq, k = h*32 + cq*8
        const size_t off = ((size_t)(bq >> 4) * 8 + h) * 512
                         + ((bq & 15) + 16 * cq) * 8;
        *(uint4*)(interm + off) = *(const uint4*)o;
    }
}

// ---------------- fused tail: gemm -> bar -> sample -> bar -> outp ---------------
// Grid 720 @ (256,3): VGPR<=168 -> 3 blocks/CU -> capacity 768, ALL resident.
// Phase 1 grid-strides 724 gemm tiles; phase 2 grid-strides 2048 sample chunks
// (stride 720 %8==0 keeps head/XCD affinity); phase 3 = out-projection (b<256).
__global__ __launch_bounds__(256, 3) void fused_tail(const unsigned short* __restrict__ val_bf,
                                                     const unsigned short* __restrict__ qry_bf,
                                                     const unsigned short* __restrict__ Wt,
                                                     const float* __restrict__ b_value,
                                                     const float* __restrict__ b_off,
                                                     const float* __restrict__ b_attn,
                                                     const float* __restrict__ refp,
                                                     unsigned short* __restrict__ v_pad,
                                                     float* __restrict__ loc_out,
                                                     float* __restrict__ attn_out,
                                                     unsigned short* __restrict__ interm,
                                                     const unsigned short* __restrict__ Wt_out,
                                                     const float* __restrict__ b_out,
                                                     float* __restrict__ out,
                                                     unsigned* __restrict__ bar) {
    const int t = threadIdx.x;

    // ---- phase 1: v-projection + offsets/attn GEMM (724 tiles over 720 blocks)
#pragma unroll 1
    for (int g = blockIdx.x; g < 724; g += TAIL_GRID) {
        if (g < 340) {
            gemm_nolds<2>(val_bf, Wt, b_value, nullptr, nullptr,
                          v_pad, nullptr, 256, g & 1, g >> 1);
        } else {
            const int g2 = g - 340;
            gemm_nolds<1>(qry_bf, Wt + (size_t)256 * KDIM, b_off, b_attn, refp,
                          loc_out, attn_out, 1536, g2 % 12, g2 / 12);
        }
    }

    gridbar(bar, TAIL_GRID);

    // ---- phase 2: bilinear sample (2048 chunks over 720 blocks)
#pragma unroll 1
    for (int sb = blockIdx.x; sb < 2048; sb += TAIL_GRID) {
        sample_chunk(sb, t, v_pad, loc_out, attn_out, interm);
        __syncthreads();   // protect wls/pls before next chunk's prologue
    }

    gridbar(bar + 1, TAIL_GRID);

    // ---- phase 3: out = interm @ W_out^T + b_out (64x64 tiles, 256 blocks)
    if (blockIdx.x < 256) {
        const int lane = t & 63, w = t >> 6;
        const int quad = lane >> 4, l16 = lane & 15;
        const int wr = w >> 1, wc = w & 1;
        const int bx = blockIdx.x & 3, by = blockIdx.x >> 2;
        const int row0 = by * 64 + wr * 32, col0 = bx * 64 + wc * 32;

        const unsigned short* ap = interm + ((size_t)(row0 >> 4) * 8) * 512 + lane * 8;
        const unsigned short* bp = Wt_out + ((size_t)(col0 >> 4) * 8) * 512 + lane * 8;

        f32x4 acc[2][2] = {};

#pragma unroll 2
        for (int kt = 0; kt < 8; ++kt) {
            short8 af[2], bf[2];
#pragma unroll
            for (int mi = 0; mi < 2; ++mi)
                af[mi] = *(const short8*)(ap + (size_t)mi * 4096 + kt * 512);
#pragma unroll
            for (int ni = 0; ni < 2; ++ni)
                bf[ni] = *(const short8*)(bp + (size_t)ni * 4096 + kt * 512);
#pragma unroll
            for (int mi = 0; mi < 2; ++mi)
#pragma unroll
                for (int ni = 0; ni < 2; ++ni)
                    acc[mi][ni] = __builtin_amdgcn_mfma_f32_16x16x32_bf16(af[mi], bf[ni],
                                                                          acc[mi][ni], 0, 0, 0);
        }

#pragma unroll
        for (int ni = 0; ni < 2; ++ni) {
            const int c = col0 + ni * 16 + l16;
            const float bv = b_out[c];
#pragma unroll
            for (int mi = 0; mi < 2; ++mi) {
                const int r0 = row0 + mi * 16 + quad * 4;
#pragma unroll
                for (int rr = 0; rr < 4; ++rr)
                    out[(size_t)(r0 + rr) * 256 + c] = acc[mi][ni][rr] + bv;
            }
        }
    }
}

// ---------------- host launch ----------------------------------------------------
extern "C" void kernel_launch(void* const* d_in, const int* in_sizes, int n_in,
                              void* d_out, int out_size, void* d_ws, size_t ws_size,
                              hipStream_t stream) {
    const float* query   = (const float*)d_in[0];
    const float* refp    = (const float*)d_in[1];
    const float* value   = (const float*)d_in[2];
    const float* W_value = (const float*)d_in[3];
    const float* b_value = (const float*)d_in[4];
    const float* W_off   = (const float*)d_in[5];
    const float* b_off   = (const float*)d_in[6];
    const float* W_attn  = (const float*)d_in[7];
    const float* b_attn  = (const float*)d_in[8];
    const float* W_out   = (const float*)d_in[9];
    const float* b_out   = (const float*)d_in[10];

    float* out      = (float*)d_out;            // [4,1024,256]
    float* loc_out  = out + 1048576;            // [4,1024,8,4,16,2]
    float* attn_out = out + 5242880;            // [4,1024,8,4,16]

    // workspace layout (26,443,784 B <= 26,476,544 proven):
    //   [0, 12156928)           v_pad   (padded HEAD-MAJOR bf16 v-projection)
    //   [12156928, 23298048)    val_bf  ALIASED WITH interm (phase 2+)
    //   [23298048, 25395200)    qry_bf
    //   [25395200, 26443776)    Wt (fragment-major, 2048 rows x 256)
    //   [26443776, 26443784)    barrier counters (re-zeroed by prep each iter)
    char* ws = (char*)d_ws;
    unsigned short* v_pad  = (unsigned short*)ws;
    unsigned short* val_bf = (unsigned short*)(ws + 12156928);
    unsigned short* interm = (unsigned short*)(ws + 12156928);    // alias
    unsigned short* qry_bf = (unsigned short*)(ws + 23298048);
    unsigned short* Wt_all = (unsigned short*)(ws + 25395200);
    unsigned*       bar    = (unsigned*)(ws + 26443776);
    const unsigned short* Wt_outp = Wt_all + (size_t)1792 * KDIM;

    const dim3 blk(256);

    // weights/value/query -> fragment-major bf16; pad borders; zero barrier
    prep<<<3992, blk, 0, stream>>>(W_value, W_off, W_attn, W_out, value, query,
                                   Wt_all, val_bf, qry_bf, v_pad, bar);

    // gemm -> bar -> sample -> bar -> out-projection (all blocks resident)
    fused_tail<<<TAIL_GRID, blk, 0, stream>>>(val_bf, qry_bf, Wt_all, b_value,
                                              b_off, b_attn, refp, v_pad,
                                              loc_out, attn_out, interm,
                                              Wt_outp, b_out, out, bar);
}

// Round 8
// 149.627 us; speedup vs baseline: 3.6139x; 3.6139x over previous
//
#include <hip/hip_runtime.h>
#include <math.h>

// Problem constants
#define BS 4
#define LQ 1024
#define EMB 256
#define NH 8
#define NL 4
#define NP 16
#define HD 32
#define LV 5440     // 64*64 + 32*32 + 16*16 + 8*8
#define LVP 5936    // padded: 66^2 + 34^2 + 18^2 + 10^2
#define KDIM 256    // all GEMMs have K = 256

typedef __attribute__((ext_vector_type(8))) short short8;  // 8 bf16 = 4 VGPRs
typedef __attribute__((ext_vector_type(4))) float f32x4;

__device__ inline unsigned short f2bf(float f) {
    unsigned u = __builtin_bit_cast(unsigned, f);
    u += 0x7fff + ((u >> 16) & 1);   // round-to-nearest-even
    return (unsigned short)(u >> 16);
}

// Fragment-major layout for a row-major [R][256] bf16 matrix:
//   tile t = (r>>4)*8 + (k>>5); slot = (r&15)+16*((k>>3)&3); elem = k&7
//   offset = t*512 + slot*8 + elem   -> one 1KB wave burst per MFMA fragment.
// v_pad layout (HEAD-MAJOR): [h][b][lvl-plane][y][x][32ch].
// R2 LESSON: LDS-staging lvl2+3 regressed — gathers already cache-hits.
// R3 LESSON: coord-hoist neutral — sample not VALU-bound.
// R4 LESSON: 8 waves/SIMD neutral — sample at structural floor since R0.
// R5 WIN: outp 64->256 blocks + fused 12 waves/CU = -4.3us.
// R6 LESSON: hipLaunchCooperativeKernel no-ops under harness graph capture.
// R7 LESSON: in-kernel grid-barrier fusion = 443us (vs ~35us as 3 launches):
//   producer->consumer handoff of v_pad (11MB dirty across 8 XCD L2s) through
//   an in-kernel fence turns every phase-2 gather into a cross-die probe
//   (286 GB/s, MfmaUtil 0.6%). Kernel-boundary L2 flush IS the cheap barrier.
//   => launch structure below (4 regular launches) is final.

// ---------------- prep ------------------------------------------------------------
__global__ __launch_bounds__(256) void prep(const float* __restrict__ Wv,
                                            const float* __restrict__ Wo,
                                            const float* __restrict__ Wa,
                                            const float* __restrict__ Wu,
                                            const float* __restrict__ value,
                                            const float* __restrict__ query,
                                            unsigned short* __restrict__ Wt,
                                            unsigned short* __restrict__ val_bf,
                                            unsigned short* __restrict__ qry_bf,
                                            unsigned short* __restrict__ v_pad) {
    const int blk = blockIdx.x;
    const int t = threadIdx.x;
    if (blk < 512) {
        __shared__ float tile[32][33];     // [k_local][n_local]
        const int n0 = (blk & 63) * 32, k0 = (blk >> 6) * 32;
        const float* src; int N, nloc;
        if (n0 < 256)       { src = Wv; N = 256;  nloc = n0; }
        else if (n0 < 1280) { src = Wo; N = 1024; nloc = n0 - 256; }
        else if (n0 < 1792) { src = Wa; N = 512;  nloc = n0 - 1280; }
        else                { src = Wu; N = 256;  nloc = n0 - 1792; }
        const int tx = t & 31, ty = t >> 5;  // ty 0..7
#pragma unroll
        for (int i = 0; i < 32; i += 8)
            tile[ty + i][tx] = src[(size_t)(k0 + ty + i) * N + nloc + tx];
        __syncthreads();
        if (t < 128) {                       // 32 n x 4 k-octets
            const int n_loc = t & 31, oct = t >> 5;
            const int n = n0 + n_loc;
            short8 h;
#pragma unroll
            for (int e = 0; e < 8; ++e) h[e] = (short)f2bf(tile[oct * 8 + e][n_loc]);
            const size_t off = ((size_t)(n >> 4) * 8 + (k0 >> 5)) * 512
                             + ((n & 15) + 16 * oct) * 8;
            *(short8*)(Wt + off) = h;
        }
    } else if (blk < 3744) {
        // fragment-major fp32->bf16: thread = (row, k-octet)
        int i; const float* src; unsigned short* dst;
        if (blk < 3232) { i = (blk - 512) * 256 + t;  src = value; dst = val_bf; }
        else            { i = (blk - 3232) * 256 + t; src = query; dst = qry_bf; }
        const int r = i >> 5, oct = i & 31, k0 = oct * 8;
        const float4 f0 = *(const float4*)(src + (size_t)r * KDIM + k0);
        const float4 f1 = *(const float4*)(src + (size_t)r * KDIM + k0 + 4);
        short8 h;
        h[0] = (short)f2bf(f0.x); h[1] = (short)f2bf(f0.y);
        h[2] = (short)f2bf(f0.z); h[3] = (short)f2bf(f0.w);
        h[4] = (short)f2bf(f1.x); h[5] = (short)f2bf(f1.y);
        h[6] = (short)f2bf(f1.z); h[7] = (short)f2bf(f1.w);
        const size_t off = ((size_t)(r >> 4) * 8 + (oct >> 2)) * 512
                         + ((r & 15) + 16 * (oct & 3)) * 8;
        *(short8*)(dst + off) = h;
    } else {
        // zero border pixels of padded v (4 batches x 496 border pixels).
        // head-major: lane32 = head*4 + channel-quad, 16B per lane.
        const int pidx = (blk - 3744) * 8 + (t >> 5);   // 0..1983
        const int lane32 = t & 31;
        const unsigned b = (unsigned)pidx / 496u;
        const unsigned rem = (unsigned)pidx - b * 496u;
        int Wd, W2, pb, i;
        if (rem < 260)      { Wd = 64; W2 = 66; pb = 0;    i = rem; }
        else if (rem < 392) { Wd = 32; W2 = 34; pb = 4356; i = rem - 260; }
        else if (rem < 460) { Wd = 16; W2 = 18; pb = 5512; i = rem - 392; }
        else                { Wd = 8;  W2 = 10; pb = 5836; i = rem - 460; }
        int y, x;
        if (i < W2)          { y = 0;      x = i; }
        else if (i < 2 * W2) { y = Wd + 1; x = i - W2; }
        else { const int j = i - 2 * W2; y = 1 + (j >> 1); x = (j & 1) ? (Wd + 1) : 0; }
        const int hh = lane32 >> 2, cq = lane32 & 3;
        const size_t off = (((size_t)(hh * BS + b) * LVP + pb + y * W2 + x) << 5)
                         + cq * 8;
        uint4 z = {0, 0, 0, 0};
        *(uint4*)(v_pad + off) = z;
    }
}

// ---------------- barrier-free no-LDS bf16 MFMA GEMM, 128x128 tile ---------------
template <int MODE>
__device__ __forceinline__ void gemm_nolds(const unsigned short* __restrict__ A,
                                           const unsigned short* __restrict__ Bt,
                                           const float* __restrict__ bias,
                                           const float* __restrict__ bias2,
                                           const float* __restrict__ refp,
                                           void* __restrict__ Cv,
                                           float* __restrict__ C2,
                                           int N, int bx, int by) {
    const int t = threadIdx.x;
    const int lane = t & 63, w = t >> 6;
    const int quad = lane >> 4, l16 = lane & 15;
    const int wr = w >> 1, wc = w & 1;
    const int row0 = by * 128, col0 = bx * 128;

    const unsigned short* ap = A  + ((size_t)((row0 >> 4) + wr * 4) * 8) * 512 + lane * 8;
    const unsigned short* bp = Bt + ((size_t)((col0 >> 4) + wc * 4) * 8) * 512 + lane * 8;

    f32x4 acc[4][4] = {};

#pragma unroll 2
    for (int kt = 0; kt < 8; ++kt) {
        short8 af[4], bf[4];
#pragma unroll
        for (int mi = 0; mi < 4; ++mi)
            af[mi] = *(const short8*)(ap + (size_t)mi * 4096 + kt * 512);
#pragma unroll
        for (int ni = 0; ni < 4; ++ni)
            bf[ni] = *(const short8*)(bp + (size_t)ni * 4096 + kt * 512);
#pragma unroll
        for (int mi = 0; mi < 4; ++mi)
#pragma unroll
            for (int ni = 0; ni < 4; ++ni)
                acc[mi][ni] = __builtin_amdgcn_mfma_f32_16x16x32_bf16(af[mi], bf[ni],
                                                                      acc[mi][ni], 0, 0, 0);
    }

    // C/D layout: col = lane&15, row = quad*4 + reg  [m89-verified, R2-R6 verified]
    if (MODE == 0) {
#pragma unroll
        for (int ni = 0; ni < 4; ++ni) {
            const int c = col0 + wc * 64 + ni * 16 + l16;
            const float bv = bias[c];
#pragma unroll
            for (int mi = 0; mi < 4; ++mi) {
                const int r0 = row0 + wr * 64 + mi * 16 + quad * 4;
#pragma unroll
                for (int rr = 0; rr < 4; ++rr)
                    ((float*)Cv)[(size_t)(r0 + rr) * N + c] = acc[mi][ni][rr] + bv;
            }
        }
    } else if (MODE == 2) {
        // v-projection into padded HEAD-MAJOR layout:
        // elem = ((head*BS + b)*LVP + pb + (y+1)*W2 + (x+1))*32 + (c&31)
        unsigned short* C = (unsigned short*)Cv;
        float bv[4];
        int cc[4];
#pragma unroll
        for (int ni = 0; ni < 4; ++ni) {
            cc[ni] = col0 + wc * 64 + ni * 16 + l16;
            bv[ni] = bias[cc[ni]];
        }
#pragma unroll
        for (int mi = 0; mi < 4; ++mi) {
#pragma unroll
            for (int rr = 0; rr < 4; ++rr) {
                const unsigned r = row0 + wr * 64 + mi * 16 + quad * 4 + rr;
                const unsigned b = r / 5440u;
                const unsigned flat = r - b * 5440u;
                unsigned y, x, W2, pb;
                if (flat < 4096)      { y = flat >> 6; x = flat & 63; W2 = 66; pb = 0; }
                else if (flat < 5120) { const unsigned f = flat - 4096; y = f >> 5; x = f & 31; W2 = 34; pb = 4356; }
                else if (flat < 5376) { const unsigned f = flat - 5120; y = f >> 4; x = f & 15; W2 = 18; pb = 5512; }
                else                  { const unsigned f = flat - 5376; y = f >> 3; x = f & 7;  W2 = 10; pb = 5836; }
                const size_t pix = (size_t)(pb + (y + 1) * W2 + (x + 1)) << 5;
#pragma unroll
                for (int ni = 0; ni < 4; ++ni) {
                    const int cc_ = cc[ni];
                    const size_t off = (((size_t)((cc_ >> 5) * BS + b) * LVP) << 5)
                                     + pix + (cc_ & 31);
                    C[off] = f2bf(acc[mi][ni][rr] + bv[ni]);
                }
            }
        }
    } else {
        const bool is_off = (col0 < 1024);   // block-uniform (1024 % 128 == 0)
        if (is_off) {
            float* C = (float*)Cv;
#pragma unroll
            for (int ni = 0; ni < 4; ++ni) {
                const int cg = col0 + wc * 64 + ni * 16 + l16;
                // cg = h*128 + l*32 + p*2 + xy
                const int xy = cg & 1, p = (cg >> 1) & 15, l = (cg >> 5) & 3;
                const float lam = (float)p * (1.0f / 15.0f);
                const float l2 = lam * lam, l3 = l2 * lam;
                const float rW = (l == 0) ? 0.015625f : (l == 1) ? 0.03125f
                                : (l == 2) ? 0.0625f : 0.125f;
                const float bv = bias[cg];
#pragma unroll
                for (int mi = 0; mi < 4; ++mi) {
                    const int r0 = row0 + wr * 64 + mi * 16 + quad * 4;
#pragma unroll
                    for (int rr = 0; rr < 4; ++rr) {
                        const int r = r0 + rr;
                        const float4 rp = *(const float4*)(refp + (size_t)r * 8 + xy * 4);
                        const float poly = rp.x * l3 + rp.y * l2 + rp.z * lam + rp.w;
                        C[(size_t)r * 1024 + cg] = poly + (acc[mi][ni][rr] + bv) * rW;
                    }
                }
            }
        } else {
            // fused softmax: this wave holds one head's 64 logits (ni*16+l16)
            // for 64 rows. Reduce over ni (in-reg) x l16 (shfl_xor 1,2,4,8).
            const int cabase = col0 - 1024 + wc * 64;   // multiple of 64
            float bv[4];
#pragma unroll
            for (int ni = 0; ni < 4; ++ni) bv[ni] = bias2[cabase + ni * 16 + l16];
#pragma unroll
            for (int mi = 0; mi < 4; ++mi) {
                const int r0 = row0 + wr * 64 + mi * 16 + quad * 4;
#pragma unroll
                for (int rr = 0; rr < 4; ++rr) {
                    float v0 = acc[mi][0][rr] + bv[0];
                    float v1 = acc[mi][1][rr] + bv[1];
                    float v2 = acc[mi][2][rr] + bv[2];
                    float v3 = acc[mi][3][rr] + bv[3];
                    float mx = fmaxf(fmaxf(v0, v1), fmaxf(v2, v3));
#pragma unroll
                    for (int mk = 1; mk < 16; mk <<= 1) mx = fmaxf(mx, __shfl_xor(mx, mk));
                    v0 = __expf(v0 - mx); v1 = __expf(v1 - mx);
                    v2 = __expf(v2 - mx); v3 = __expf(v3 - mx);
                    float s = v0 + v1 + v2 + v3;
#pragma unroll
                    for (int mk = 1; mk < 16; mk <<= 1) s += __shfl_xor(s, mk);
                    const float inv = 1.0f / s;
                    const size_t rb = (size_t)(r0 + rr) * 512 + cabase + l16;
                    C2[rb]      = v0 * inv;
                    C2[rb + 16] = v1 * inv;
                    C2[rb + 32] = v2 * inv;
                    C2[rb + 48] = v3 * inv;
                }
            }
        }
    }
}

// One launch: v-projection (blocks 0..339) + fused offsets/attn GEMM (340..723).
// 12 waves/CU — main loop is L2-latency-bound (fragment loads miss L1).
__global__ __launch_bounds__(256, 3) void gemm_fused(const unsigned short* __restrict__ val_bf,
                                                     const unsigned short* __restrict__ qry_bf,
                                                     const unsigned short* __restrict__ Wt,
                                                     const float* __restrict__ b_value,
                                                     const float* __restrict__ b_off,
                                                     const float* __restrict__ b_attn,
                                                     const float* __restrict__ refp,
                                                     unsigned short* __restrict__ v_pad,
                                                     float* __restrict__ loc_out,
                                                     float* __restrict__ attn_out) {
    const int b = blockIdx.x;
    if (b < 340) {
        gemm_nolds<2>(val_bf, Wt, b_value, nullptr, nullptr,
                      v_pad, nullptr, 256, b & 1, b >> 1);
    } else {
        const int b2 = b - 340;
        gemm_nolds<1>(qry_bf, Wt + (size_t)256 * KDIM, b_off, b_attn, refp,
                      loc_out, attn_out, 1536, b2 % 12, b2 / 12);
    }
}

// out-projection: 64x64 tiles -> 256 blocks (full CU coverage, R5 win).
__global__ __launch_bounds__(256, 8) void gemm_outp64(const unsigned short* __restrict__ interm,
                                                      const unsigned short* __restrict__ Wt_out,
                                                      const float* __restrict__ b_out,
                                                      float* __restrict__ out) {
    const int t = threadIdx.x;
    const int lane = t & 63, w = t >> 6;
    const int quad = lane >> 4, l16 = lane & 15;
    const int wr = w >> 1, wc = w & 1;
    const int bx = blockIdx.x & 3, by = blockIdx.x >> 2;
    const int row0 = by * 64 + wr * 32, col0 = bx * 64 + wc * 32;

    const unsigned short* ap = interm + ((size_t)(row0 >> 4) * 8) * 512 + lane * 8;
    const unsigned short* bp = Wt_out + ((size_t)(col0 >> 4) * 8) * 512 + lane * 8;

    f32x4 acc[2][2] = {};

#pragma unroll 2
    for (int kt = 0; kt < 8; ++kt) {
        short8 af[2], bf[2];
#pragma unroll
        for (int mi = 0; mi < 2; ++mi)
            af[mi] = *(const short8*)(ap + (size_t)mi * 4096 + kt * 512);
#pragma unroll
        for (int ni = 0; ni < 2; ++ni)
            bf[ni] = *(const short8*)(bp + (size_t)ni * 4096 + kt * 512);
#pragma unroll
        for (int mi = 0; mi < 2; ++mi)
#pragma unroll
            for (int ni = 0; ni < 2; ++ni)
                acc[mi][ni] = __builtin_amdgcn_mfma_f32_16x16x32_bf16(af[mi], bf[ni],
                                                                      acc[mi][ni], 0, 0, 0);
    }

#pragma unroll
    for (int ni = 0; ni < 2; ++ni) {
        const int c = col0 + ni * 16 + l16;
        const float bv = b_out[c];
#pragma unroll
        for (int mi = 0; mi < 2; ++mi) {
            const int r0 = row0 + mi * 16 + quad * 4;
#pragma unroll
            for (int rr = 0; rr < 4; ++rr)
                out[(size_t)(r0 + rr) * 256 + c] = acc[mi][ni][rr] + bv;
        }
    }
}

// ---------------- bilinear sampling + attention weighting (head-major bf16 v) ----
// Block = one head (h = blockIdx&7, XCD-affine) x 16 (b,q) groups.
// 8 waves/SIMD; weights/offsets precomputed in block prologue.
// At structural floor per R2/R3/R4 nulls.
__global__ __launch_bounds__(256, 8) void sample_kernel(const unsigned short* __restrict__ v,
                                                        const float* __restrict__ loc,
                                                        const float* __restrict__ attn,
                                                        unsigned short* __restrict__ interm) {
    const int t = threadIdx.x;
    const int h = blockIdx.x & 7;                    // head == XCD slot
    const int bq0 = (blockIdx.x >> 3) * 16;          // block's first (b,q) group

    __shared__ float4 wls[1088];                     // padded: phys = idx + (idx>>4)
    __shared__ unsigned short pls[1088];             // pixel index (elem off >> 5)

    // ---- prologue: compute 1024 points' weights+offsets once ----
    {
        const int gloc = t >> 4;          // 0..15
        const int lvl  = (t >> 2) & 3;    // 0..3
        const int pq   = t & 3;           // point quad -> points pq*4..pq*4+3
        const int g = (bq0 + gloc) * 8 + h;
        const float4 l01 = *(const float4*)(loc + (size_t)g * 128 + lvl * 32 + pq * 8);
        const float4 l23 = *(const float4*)(loc + (size_t)g * 128 + lvl * 32 + pq * 8 + 4);
        const float4 av  = *(const float4*)(attn + (size_t)g * 64 + lvl * 16 + pq * 4);
        const int Wd = 64 >> lvl;
        const float Wf = (float)Wd;
        const int W2 = Wd + 2;
        const int pb = (lvl == 0) ? 0 : (lvl == 1) ? 4356 : (lvl == 2) ? 5512 : 5836;
        const int ibase = gloc * 64 + lvl * 16 + pq * 4;
        const int pbase = ibase + (ibase >> 4);      // padded physical base
        const float lx[4] = {l01.x, l01.z, l23.x, l23.z};
        const float ly[4] = {l01.y, l01.w, l23.y, l23.w};
        const float aw[4] = {av.x, av.y, av.z, av.w};
#pragma unroll
        for (int k = 0; k < 4; ++k) {
            const float x = fmaf(lx[k], Wf, -0.5f);
            const float y = fmaf(ly[k], Wf, -0.5f);
            const float xc = fminf(fmaxf(x, -1.0f), Wf);
            const float yc = fminf(fmaxf(y, -1.0f), Wf);
            const float x0f = fminf(floorf(xc), Wf - 1.0f);
            const float y0f = fminf(floorf(yc), Wf - 1.0f);
            const float wx = xc - x0f, wy = yc - y0f;
            const float iwx = 1.0f - wx, iwy = 1.0f - wy;
            const int px = (int)x0f + 1;          // [0, W]
            const int py = (int)y0f + 1;          // [0, W]
            const float a = aw[k];
            wls[pbase + k] = make_float4(iwx * iwy * a, wx * iwy * a,
                                         iwx * wy * a,  wx * wy * a);
            pls[pbase + k] = (unsigned short)(pb + py * W2 + px);
        }
    }
    __syncthreads();

    // ---- main gather loop ----
    const int bq = bq0 + (t >> 4);
    const int l16i = t & 15;
    const int lvl = l16i >> 2;                  // level 0..3
    const int cq  = l16i & 3;                   // channel octet (8 bf16)
    const int b = bq >> 10;                     // block-uniform (16 | 1024)
    const int rowoff = ((64 >> lvl) + 2) * 32;  // next-row elem stride

    const unsigned short* vl = v + (((size_t)(h * BS + b) * LVP) << 5) + cq * 8;
    const int wbase = (t >> 4) * 64 + lvl * 16;
    const int wphys = wbase + (wbase >> 4);     // (idx>>4) const over p in [0,16)

    float2 acc2[4] = {};

    auto cvt2 = [](unsigned d) {
        uint2 u; u.x = d << 16; u.y = d & 0xffff0000u;
        return __builtin_bit_cast(float2, u);
    };
    auto cadd = [&](const uint4 q, float wgt) {
        const float2 w2 = make_float2(wgt, wgt);
        acc2[0] += cvt2(q.x) * w2;
        acc2[1] += cvt2(q.y) * w2;
        acc2[2] += cvt2(q.z) * w2;
        acc2[3] += cvt2(q.w) * w2;
    };

#pragma unroll 1
    for (int p = 0; p < 16; ++p) {
        const float4 w = wls[wphys + p];
        const int base = ((int)pls[wphys + p]) << 5;
        const unsigned short* ptr = vl + base;
        const uint4 g00 = *(const uint4*)(ptr);
        const uint4 g10 = *(const uint4*)(ptr + 32);
        const uint4 g01 = *(const uint4*)(ptr + rowoff);
        const uint4 g11 = *(const uint4*)(ptr + rowoff + 32);
        cadd(g00, w.x); cadd(g10, w.y); cadd(g01, w.z); cadd(g11, w.w);
    }

    float a[8] = {acc2[0].x, acc2[0].y, acc2[1].x, acc2[1].y,
                  acc2[2].x, acc2[2].y, acc2[3].x, acc2[3].y};
    // reduce across the 4 level-quads (lane bits 2,3)
#pragma unroll
    for (int m = 4; m <= 8; m <<= 1)
#pragma unroll
        for (int k = 0; k < 8; ++k) a[k] += __shfl_xor(a[k], m);

    if (lvl == 0) {
        unsigned short o[8];
#pragma unroll
        for (int k = 0; k < 8; ++k) o[k] = f2bf(a[k]);
        // fragment-major interm: row = bq, k = h*32 + cq*8
        const size_t off = ((size_t)(bq >> 4) * 8 + h) * 512
                         + ((bq & 15) + 16 * cq) * 8;
        *(uint4*)(interm + off) = *(const uint4*)o;
    }
}

// ---------------- host launch ----------------------------------------------------
extern "C" void kernel_launch(void* const* d_in, const int* in_sizes, int n_in,
                              void* d_out, int out_size, void* d_ws, size_t ws_size,
                              hipStream_t stream) {
    const float* query   = (const float*)d_in[0];
    const float* refp    = (const float*)d_in[1];
    const float* value   = (const float*)d_in[2];
    const float* W_value = (const float*)d_in[3];
    const float* b_value = (const float*)d_in[4];
    const float* W_off   = (const float*)d_in[5];
    const float* b_off   = (const float*)d_in[6];
    const float* W_attn  = (const float*)d_in[7];
    const float* b_attn  = (const float*)d_in[8];
    const float* W_out   = (const float*)d_in[9];
    const float* b_out   = (const float*)d_in[10];

    float* out      = (float*)d_out;            // [4,1024,256]
    float* loc_out  = out + 1048576;            // [4,1024,8,4,16,2]
    float* attn_out = out + 5242880;            // [4,1024,8,4,16]

    // workspace layout (26,443,776 B):
    //   [0, 12156928)           v_pad   (padded HEAD-MAJOR bf16 v-projection)
    //   [12156928, 23298048)    val_bf  (launches 1-2)  ALIASED WITH interm (3-4)
    //   [23298048, 25395200)    qry_bf
    //   [25395200, 26443776)    Wt (fragment-major, 2048 rows x 256)
    char* ws = (char*)d_ws;
    unsigned short* v_pad  = (unsigned short*)ws;
    unsigned short* val_bf = (unsigned short*)(ws + 12156928);
    unsigned short* interm = (unsigned short*)(ws + 12156928);    // alias
    unsigned short* qry_bf = (unsigned short*)(ws + 23298048);
    unsigned short* Wt_all = (unsigned short*)(ws + 25395200);

    const dim3 blk(256);

    // weights -> fragment-major bf16; value/query -> fragment-major bf16; pad borders
    prep<<<3992, blk, 0, stream>>>(W_value, W_off, W_attn, W_out, value, query,
                                   Wt_all, val_bf, qry_bf, v_pad);

    // v-projection into padded layout (340 blocks) + fused offsets/attn GEMM (384)
    gemm_fused<<<724, blk, 0, stream>>>(val_bf, qry_bf, Wt_all, b_value, b_off,
                                        b_attn, refp, v_pad, loc_out, attn_out);

    // bilinear gather + attention weighting -> interm (fragment-major, overwrites val_bf)
    sample_kernel<<<(BS * LQ * NH) / 16, blk, 0, stream>>>(v_pad, loc_out, attn_out, interm);

    // output = interm @ W_out^T + b_out  (256 blocks, full CU coverage)
    gemm_outp64<<<256, blk, 0, stream>>>(interm, Wt_all + (size_t)1792 * KDIM, b_out, out);
}